// Round 7
// baseline (528.200 us; speedup 1.0000x reference)
//
#include <hip/hip_runtime.h>
#include <cstdint>
#include <cstddef>

typedef __attribute__((ext_vector_type(8))) short short8;
typedef __attribute__((ext_vector_type(16))) float floatx16;

__device__ __forceinline__ unsigned short f2bf(float f) {
    union { float f; unsigned int u; } v; v.f = f;
    unsigned int r = v.u + 0x7fffu + ((v.u >> 16) & 1u);
    return (unsigned short)(r >> 16);
}

__device__ __forceinline__ void glds16(const void* g, void* l) {
    __builtin_amdgcn_global_load_lds(
        (const __attribute__((address_space(1))) void*)g,
        (__attribute__((address_space(3))) void*)l, 16, 0, 0);
}

// C/D layout (m74/m101, verified): col = lane&31, row = (r&3)+8*(r>>2)+4*kg
#define EPI_ROW(r, kg) (((r) & 3) + 8 * ((r) >> 2) + 4 * (kg))

// ============ 128x128 core, 2-barrier loop (measured 810 TF @ 4 blk/CU) ======
// Swizzle (verified: SQ_LDS_BANK_CONFLICT == 0): key(row)=(row^(row>>3))&7
__device__ __forceinline__ void gemm_core(
    const unsigned short* __restrict__ Ab, int ldA,
    const unsigned short* __restrict__ Bb, int ldB,
    int K,
    unsigned short* __restrict__ As, unsigned short* __restrict__ Bs,
    floatx16 (&acc)[2][2])
{
    const int tid = threadIdx.x;
    const int wave = tid >> 6, lane = tid & 63;

    const unsigned short* gA[4];
    const unsigned short* gB[4];
#pragma unroll
    for (int i = 0; i < 4; ++i) {
        const int c = i * 256 + tid;
        const int row = c >> 3;
        const int l = (c & 7) ^ ((row ^ (row >> 3)) & 7);
        gA[i] = Ab + (size_t)row * ldA + l * 8;
        gB[i] = Bb + (size_t)row * ldB + l * 8;
    }
    const int arow = (wave >> 1) * 64 + (lane & 31);
    const int brow = (wave & 1) * 64 + (lane & 31);
    const int kg = lane >> 5;
    const int sw = (lane & 7) ^ ((lane >> 3) & 3);
    const unsigned short* pa = As + arow * 64;
    const unsigned short* pb = Bs + brow * 64;

    for (int k0 = 0; k0 < K; k0 += 64) {
#pragma unroll
        for (int i = 0; i < 4; ++i)
            glds16(gA[i] + k0, As + (size_t)(i * 256 + wave * 64) * 8);
#pragma unroll
        for (int i = 0; i < 4; ++i)
            glds16(gB[i] + k0, Bs + (size_t)(i * 256 + wave * 64) * 8);
        __syncthreads();
#pragma unroll
        for (int s = 0; s < 4; ++s) {
            const int o0 = ((2 * s + kg) ^ sw) * 8;
            const int o1 = o0 ^ 32;
            short8 a0 = *(const short8*)(pa + o0);
            short8 a1 = *(const short8*)(pa + 32 * 64 + o1);
            short8 b0 = *(const short8*)(pb + o0);
            short8 b1 = *(const short8*)(pb + 32 * 64 + o1);
            acc[0][0] = __builtin_amdgcn_mfma_f32_32x32x16_bf16(a0, b0, acc[0][0], 0, 0, 0);
            acc[0][1] = __builtin_amdgcn_mfma_f32_32x32x16_bf16(a0, b1, acc[0][1], 0, 0, 0);
            acc[1][0] = __builtin_amdgcn_mfma_f32_32x32x16_bf16(a1, b0, acc[1][0], 0, 0, 0);
            acc[1][1] = __builtin_amdgcn_mfma_f32_32x32x16_bf16(a1, b1, acc[1][1], 0, 0, 0);
        }
        __syncthreads();
    }
}

// ====== prep: fp32->bf16 converts + weight transpose-converts + zeroing ======
__global__ __launch_bounds__(256) void prep_kernel(
    const float* __restrict__ x, const float* __restrict__ ctx,
    const float* __restrict__ Wq, const float* __restrict__ Wk, const float* __restrict__ Wv,
    unsigned short* __restrict__ xb, unsigned short* __restrict__ cb,
    unsigned short* __restrict__ Wt0, unsigned short* __restrict__ WtKV,
    float* __restrict__ lrow, unsigned int* __restrict__ cnt) {
    const int b = blockIdx.x;
    if (b < 16384) {
        int i = b * 256 + threadIdx.x;
        const float* in; unsigned short* out; int j;
        if (i < 2097152) { in = x; out = xb; j = i; }
        else { in = ctx; out = cb; j = i - 2097152; }
        float4 v = reinterpret_cast<const float4*>(in)[j];
        ushort4 o;
        o.x = f2bf(v.x); o.y = f2bf(v.y); o.z = f2bf(v.z); o.w = f2bf(v.w);
        reinterpret_cast<ushort4*>(out)[j] = o;
    } else if (b < 19456) {
        // weight transpose, widened: float4 loads, ushort4 stores
        __shared__ float tile[32][33];
        const int z = b - 16384;
        const int w = z >> 10, t = z & 1023;
        const float* in = (w == 0) ? Wq : (w == 1) ? Wk : Wv;
        unsigned short* out = (w == 0) ? Wt0 : (w == 1) ? WtKV : (WtKV + 1024 * 1024);
        const int c0 = (t & 31) * 32, r0 = (t >> 5) * 32;
        const int tq = threadIdx.x & 7, tr = threadIdx.x >> 3;   // 8 x 32
        float4 v = *reinterpret_cast<const float4*>(&in[(size_t)(r0 + tr) * 1024 + c0 + tq * 4]);
        tile[tr][tq * 4 + 0] = v.x; tile[tr][tq * 4 + 1] = v.y;
        tile[tr][tq * 4 + 2] = v.z; tile[tr][tq * 4 + 3] = v.w;
        __syncthreads();
        ushort4 u;
        u.x = f2bf(tile[tq * 4 + 0][tr]);
        u.y = f2bf(tile[tq * 4 + 1][tr]);
        u.z = f2bf(tile[tq * 4 + 2][tr]);
        u.w = f2bf(tile[tq * 4 + 3][tr]);
        *reinterpret_cast<ushort4*>(&out[(size_t)(c0 + tr) * 1024 + r0 + tq * 4]) = u;
    } else {
        // zero lrow (8192 fp32 = 2048 float4 over 8 blocks) + 64 stripe counters
        const int i = (b - 19456) * 256 + threadIdx.x;
        reinterpret_cast<float4*>(lrow)[i] = float4{0.f, 0.f, 0.f, 0.f};
        if (b == 19463 && threadIdx.x < 64) cnt[threadIdx.x] = 0u;
    }
}

// ============ mega QKV: 1536 blocks of 128x128; Q (512) + KV (1024) ==========
// (R0-verified: ~64-66 us, MfmaUtil 33-34%, FETCH ~52 MB, XCD co-location)
__global__ __launch_bounds__(256, 4) void qkv_kernel(
    const unsigned short* __restrict__ xb, const unsigned short* __restrict__ cb,
    const unsigned short* __restrict__ WtQ, const unsigned short* __restrict__ WtKV,
    const float* __restrict__ bq, const float* __restrict__ bk, const float* __restrict__ bv,
    unsigned short* __restrict__ Qb, unsigned short* __restrict__ Kb,
    unsigned short* __restrict__ Vt) {
    __shared__ unsigned short As[128 * 64];
    __shared__ unsigned short Bs[128 * 64];
    const int i = blockIdx.x;
    const bool isQ = i < 512;
    int by, bxcol;
    const unsigned short *A, *B;
    if (isQ) {
        const int slot = i >> 3;
        by = (i & 7) + 8 * (slot & 7);
        const int bx = slot >> 3; bxcol = bx * 128;
        A = xb + (size_t)by * 128 * 1024;
        B = WtQ + (size_t)bx * 128 * 1024;
    } else {
        const int j = i - 512;
        const int slot = j >> 3;
        by = (j & 7) + 8 * (slot & 7);
        const int bx = slot >> 3; bxcol = bx * 128;
        A = cb + (size_t)by * 128 * 1024;
        B = WtKV + (size_t)bx * 128 * 1024;
    }
    floatx16 acc[2][2];
#pragma unroll
    for (int a = 0; a < 2; ++a)
#pragma unroll
        for (int bj = 0; bj < 2; ++bj)
#pragma unroll
            for (int r = 0; r < 16; ++r) acc[a][bj][r] = 0.f;

    gemm_core(A, 1024, B, 1024, 1024, As, Bs, acc);

    const int wave = threadIdx.x >> 6, lane = threadIdx.x & 63;
    const int kg = lane >> 5;
    const int cm = by * 128 + (wave >> 1) * 64;
    const int cn = bxcol + (wave & 1) * 64 + (lane & 31);
    if (isQ || bxcol < 1024) {
        unsigned short* O = isQ ? Qb : Kb;
        const float* bias = isQ ? bq : bk;
#pragma unroll
        for (int nt = 0; nt < 2; ++nt) {
            const int col = cn + nt * 32;
            const float bvv = bias[col];
#pragma unroll
            for (int mt = 0; mt < 2; ++mt)
#pragma unroll
                for (int r = 0; r < 16; ++r) {
                    const int row = cm + mt * 32 + EPI_ROW(r, kg);
                    O[(size_t)row * 1024 + col] = f2bf(acc[mt][nt][r] + bvv);
                }
        }
    } else {
        // V half -> transposed write: Vt[b][colv][q]; 4 consecutive q per reg-quad
#pragma unroll
        for (int nt = 0; nt < 2; ++nt) {
            const int colv = cn + nt * 32 - 1024;
            const float bvv = bv[colv];
#pragma unroll
            for (int mt = 0; mt < 2; ++mt) {
                const int rowg = cm + mt * 32 + 4 * kg;
                const int b = rowg >> 11, qb = rowg & 2047;
#pragma unroll
                for (int g = 0; g < 4; ++g) {
                    const int q = qb + 8 * g;
                    ushort4 u;
                    u.x = f2bf(acc[mt][nt][g * 4 + 0] + bvv);
                    u.y = f2bf(acc[mt][nt][g * 4 + 1] + bvv);
                    u.z = f2bf(acc[mt][nt][g * 4 + 2] + bvv);
                    u.w = f2bf(acc[mt][nt][g * 4 + 3] + bvv);
                    *reinterpret_cast<ushort4*>(Vt + (size_t)b * 2097152 + (size_t)colv * 2048 + q) = u;
                }
            }
        }
    }
}

// ===== fused qkt (bid 0..1023) + pv (bid 1024..1535), stripe-pipelined =======
// Stripe g = z*16+by (64 stripes). Producers: bid = g*16 + bx -> stripe g's 16
// tiles are CONTIGUOUS bids, so stripes complete in dispatch order and pv
// consumers (bid 1024 + g*8 + bx_out) start while later producers still run.
// Sync: per-stripe counter, agent-scope release add / acquire load.
// Deadlock-free: 512 potential waiters < 1024 co-resident blocks (32KB LDS,
// 64 VGPR, 4 blk/CU) -- producers never wait, so some producer always runs.
// Cross-XCD re-reads (Qb/Kb/Sb/Vt ~134 MB) are L3-resident (256 MB).
__global__ __launch_bounds__(256, 4) void qktpv_kernel(
    const unsigned short* __restrict__ Qb, const unsigned short* __restrict__ Kb,
    const unsigned short* __restrict__ Vt, unsigned short* __restrict__ Sb,
    float* __restrict__ lrow, unsigned int* __restrict__ cnt,
    float* __restrict__ out) {
    __shared__ unsigned short As[128 * 64];
    __shared__ unsigned short Bs[128 * 64];
    const int bid = blockIdx.x;

    if (bid < 1024) {
        // ---------------- qkt producer (R0-verified body) ----------------
        const int g = bid >> 4;                  // stripe 0..63
        const int z = g >> 4, by = g & 15;
        const int bx = bid & 15;
        const unsigned short* A = Qb + (size_t)z * 2097152 + (size_t)by * 128 * 1024;
        const unsigned short* B = Kb + (size_t)z * 2097152 + (size_t)bx * 128 * 1024;
        floatx16 acc[2][2];
#pragma unroll
        for (int a = 0; a < 2; ++a)
#pragma unroll
            for (int bj = 0; bj < 2; ++bj)
#pragma unroll
                for (int r = 0; r < 16; ++r) acc[a][bj][r] = 0.f;

        gemm_core(A, 1024, B, 1024, 1024, As, Bs, acc);

        const int wave = threadIdx.x >> 6, lane = threadIdx.x & 63;
        const int kg = lane >> 5;
        unsigned short* C = Sb + (size_t)z * 4194304;
        float* lz = lrow + z * 2048;
        const int cm = by * 128 + (wave >> 1) * 64;
        const int cn = bx * 128 + (wave & 1) * 64 + (lane & 31);
#pragma unroll
        for (int mt = 0; mt < 2; ++mt)
#pragma unroll
            for (int r = 0; r < 16; ++r) {
                const int row = cm + mt * 32 + EPI_ROW(r, kg);
                const float e0 = __expf(acc[mt][0][r] * 0.03125f);
                const float e1 = __expf(acc[mt][1][r] * 0.03125f);
                C[(size_t)row * 2048 + cn] = f2bf(e0);
                C[(size_t)row * 2048 + cn + 32] = f2bf(e1);
                float s = e0 + e1;
                s += __shfl_xor(s, 1);  s += __shfl_xor(s, 2);
                s += __shfl_xor(s, 4);  s += __shfl_xor(s, 8);
                s += __shfl_xor(s, 16);
                if ((lane & 31) == (mt * 16 + r)) atomicAdd(&lz[row], s);
            }
        // signal stripe g: all S stores + lrow atomics of this tile done
        __threadfence();
        __syncthreads();
        if (threadIdx.x == 0)
            __hip_atomic_fetch_add(&cnt[g], 1u,
                                   __ATOMIC_RELEASE, __HIP_MEMORY_SCOPE_AGENT);
    } else {
        // ---------------- pv consumer (R0-verified body) ----------------
        const int c = bid - 1024;                // 0..511
        const int g = c >> 3;                    // stripe, same order as producers
        const int z = g >> 4, by = g & 15;
        const int bx = c & 7;
        if (threadIdx.x == 0) {
            while (__hip_atomic_load(&cnt[g],
                                     __ATOMIC_ACQUIRE, __HIP_MEMORY_SCOPE_AGENT) < 16u)
                __builtin_amdgcn_s_sleep(8);
        }
        __syncthreads();
        __threadfence();

        const unsigned short* A = Sb + (size_t)z * 4194304 + (size_t)by * 128 * 2048;
        const unsigned short* B = Vt + (size_t)z * 2097152 + (size_t)bx * 128 * 2048;
        floatx16 acc[2][2];
#pragma unroll
        for (int a = 0; a < 2; ++a)
#pragma unroll
            for (int bj = 0; bj < 2; ++bj)
#pragma unroll
                for (int r = 0; r < 16; ++r) acc[a][bj][r] = 0.f;

        gemm_core(A, 2048, B, 2048, 2048, As, Bs, acc);

        const int wave = threadIdx.x >> 6, lane = threadIdx.x & 63;
        const int kg = lane >> 5;
        float* C = out + (size_t)z * 2097152;
        const float* lz = lrow + z * 2048;
        const int cm = by * 128 + (wave >> 1) * 64;
        const int cn = bx * 128 + (wave & 1) * 64 + (lane & 31);
#pragma unroll
        for (int mt = 0; mt < 2; ++mt)
#pragma unroll
            for (int r = 0; r < 16; ++r) {
                const int row = cm + mt * 32 + EPI_ROW(r, kg);
                const float inv = 1.0f / lz[row];
                C[(size_t)row * 1024 + cn] = acc[mt][0][r] * inv;
                C[(size_t)row * 1024 + cn + 32] = acc[mt][1][r] * inv;
            }
    }
}

extern "C" void kernel_launch(void* const* d_in, const int* in_sizes, int n_in,
                              void* d_out, int out_size, void* d_ws, size_t ws_size,
                              hipStream_t stream) {
    const float* x   = (const float*)d_in[0];
    const float* ctx = (const float*)d_in[1];
    const float* Wq  = (const float*)d_in[2];
    const float* bq  = (const float*)d_in[3];
    const float* Wk  = (const float*)d_in[4];
    const float* bk  = (const float*)d_in[5];
    const float* Wv  = (const float*)d_in[6];
    const float* bv  = (const float*)d_in[7];
    float* out = (float*)d_out;

    const size_t MB = 1024 * 1024;
    char* ws = (char*)d_ws;
    unsigned short* xb   = (unsigned short*)(ws + 0 * MB);
    unsigned short* cb   = (unsigned short*)(ws + 16 * MB);
    unsigned short* Qb   = (unsigned short*)(ws + 32 * MB);
    unsigned short* Kb   = (unsigned short*)(ws + 48 * MB);
    unsigned short* Vt   = (unsigned short*)(ws + 64 * MB);
    unsigned short* Wt0  = (unsigned short*)(ws + 80 * MB);
    unsigned short* WtKV = (unsigned short*)(ws + 82 * MB);
    unsigned short* Sb   = (unsigned short*)(ws + 86 * MB);
    float*          lrow = (float*)(ws + 118 * MB);            // 8192 fp32
    unsigned int*   cnt  = (unsigned int*)(ws + 118 * MB + 32768); // 64 u32

    prep_kernel<<<16384 + 3072 + 8, 256, 0, stream>>>(
        x, ctx, Wq, Wk, Wv, xb, cb, Wt0, WtKV, lrow, cnt);
    qkv_kernel<<<1536, 256, 0, stream>>>(xb, cb, Wt0, WtKV, bq, bk, bv, Qb, Kb, Vt);
    qktpv_kernel<<<1536, 256, 0, stream>>>(Qb, Kb, Vt, Sb, lrow, cnt, out);
}

// Round 8
// 271.504 us; speedup vs baseline: 1.9455x; 1.9455x over previous
//
#include <hip/hip_runtime.h>
#include <cstdint>
#include <cstddef>

typedef __attribute__((ext_vector_type(8))) short short8;
typedef __attribute__((ext_vector_type(16))) float floatx16;

__device__ __forceinline__ unsigned short f2bf(float f) {
    union { float f; unsigned int u; } v; v.f = f;
    unsigned int r = v.u + 0x7fffu + ((v.u >> 16) & 1u);
    return (unsigned short)(r >> 16);
}

__device__ __forceinline__ void glds16(const void* g, void* l) {
    __builtin_amdgcn_global_load_lds(
        (const __attribute__((address_space(1))) void*)g,
        (__attribute__((address_space(3))) void*)l, 16, 0, 0);
}

// C/D layout (m74/m101, verified): col = lane&31, row = (r&3)+8*(r>>2)+4*kg
#define EPI_ROW(r, kg) (((r) & 3) + 8 * ((r) >> 2) + 4 * (kg))

// ============ 128x128 core, 2-barrier loop (measured 810 TF @ 4 blk/CU) ======
// Swizzle (verified: SQ_LDS_BANK_CONFLICT == 0): key(row)=(row^(row>>3))&7
__device__ __forceinline__ void gemm_core(
    const unsigned short* __restrict__ Ab, int ldA,
    const unsigned short* __restrict__ Bb, int ldB,
    int K,
    unsigned short* __restrict__ As, unsigned short* __restrict__ Bs,
    floatx16 (&acc)[2][2])
{
    const int tid = threadIdx.x;
    const int wave = tid >> 6, lane = tid & 63;

    const unsigned short* gA[4];
    const unsigned short* gB[4];
#pragma unroll
    for (int i = 0; i < 4; ++i) {
        const int c = i * 256 + tid;
        const int row = c >> 3;
        const int l = (c & 7) ^ ((row ^ (row >> 3)) & 7);
        gA[i] = Ab + (size_t)row * ldA + l * 8;
        gB[i] = Bb + (size_t)row * ldB + l * 8;
    }
    const int arow = (wave >> 1) * 64 + (lane & 31);
    const int brow = (wave & 1) * 64 + (lane & 31);
    const int kg = lane >> 5;
    const int sw = (lane & 7) ^ ((lane >> 3) & 3);
    const unsigned short* pa = As + arow * 64;
    const unsigned short* pb = Bs + brow * 64;

    for (int k0 = 0; k0 < K; k0 += 64) {
#pragma unroll
        for (int i = 0; i < 4; ++i)
            glds16(gA[i] + k0, As + (size_t)(i * 256 + wave * 64) * 8);
#pragma unroll
        for (int i = 0; i < 4; ++i)
            glds16(gB[i] + k0, Bs + (size_t)(i * 256 + wave * 64) * 8);
        __syncthreads();
#pragma unroll
        for (int s = 0; s < 4; ++s) {
            const int o0 = ((2 * s + kg) ^ sw) * 8;
            const int o1 = o0 ^ 32;
            short8 a0 = *(const short8*)(pa + o0);
            short8 a1 = *(const short8*)(pa + 32 * 64 + o1);
            short8 b0 = *(const short8*)(pb + o0);
            short8 b1 = *(const short8*)(pb + 32 * 64 + o1);
            acc[0][0] = __builtin_amdgcn_mfma_f32_32x32x16_bf16(a0, b0, acc[0][0], 0, 0, 0);
            acc[0][1] = __builtin_amdgcn_mfma_f32_32x32x16_bf16(a0, b1, acc[0][1], 0, 0, 0);
            acc[1][0] = __builtin_amdgcn_mfma_f32_32x32x16_bf16(a1, b0, acc[1][0], 0, 0, 0);
            acc[1][1] = __builtin_amdgcn_mfma_f32_32x32x16_bf16(a1, b1, acc[1][1], 0, 0, 0);
        }
        __syncthreads();
    }
}

// ====== prep: fp32->bf16 converts + weight transpose-converts + lrow zero ====
// Transpose widened (validated in R7 run): float4 loads, ushort4 stores.
__global__ __launch_bounds__(256) void prep_kernel(
    const float* __restrict__ x, const float* __restrict__ ctx,
    const float* __restrict__ Wq, const float* __restrict__ Wk, const float* __restrict__ Wv,
    unsigned short* __restrict__ xb, unsigned short* __restrict__ cb,
    unsigned short* __restrict__ Wt0, unsigned short* __restrict__ WtKV,
    float* __restrict__ lrow) {
    const int b = blockIdx.x;
    if (b < 16384) {
        int i = b * 256 + threadIdx.x;
        const float* in; unsigned short* out; int j;
        if (i < 2097152) { in = x; out = xb; j = i; }
        else { in = ctx; out = cb; j = i - 2097152; }
        float4 v = reinterpret_cast<const float4*>(in)[j];
        ushort4 o;
        o.x = f2bf(v.x); o.y = f2bf(v.y); o.z = f2bf(v.z); o.w = f2bf(v.w);
        reinterpret_cast<ushort4*>(out)[j] = o;
    } else if (b < 19456) {
        // weight transpose, widened: float4 loads, ushort4 stores
        __shared__ float tile[32][33];
        const int z = b - 16384;
        const int w = z >> 10, t = z & 1023;
        const float* in = (w == 0) ? Wq : (w == 1) ? Wk : Wv;
        unsigned short* out = (w == 0) ? Wt0 : (w == 1) ? WtKV : (WtKV + 1024 * 1024);
        const int c0 = (t & 31) * 32, r0 = (t >> 5) * 32;
        const int tq = threadIdx.x & 7, tr = threadIdx.x >> 3;   // 8 x 32
        float4 v = *reinterpret_cast<const float4*>(&in[(size_t)(r0 + tr) * 1024 + c0 + tq * 4]);
        tile[tr][tq * 4 + 0] = v.x; tile[tr][tq * 4 + 1] = v.y;
        tile[tr][tq * 4 + 2] = v.z; tile[tr][tq * 4 + 3] = v.w;
        __syncthreads();
        ushort4 u;
        u.x = f2bf(tile[tq * 4 + 0][tr]);
        u.y = f2bf(tile[tq * 4 + 1][tr]);
        u.z = f2bf(tile[tq * 4 + 2][tr]);
        u.w = f2bf(tile[tq * 4 + 3][tr]);
        *reinterpret_cast<ushort4*>(&out[(size_t)(c0 + tr) * 1024 + r0 + tq * 4]) = u;
    } else {
        // zero lrow: 8192 floats = 2048 float4 over 8 blocks x 256 threads
        const int i = (b - 19456) * 256 + threadIdx.x;
        reinterpret_cast<float4*>(lrow)[i] = float4{0.f, 0.f, 0.f, 0.f};
    }
}

// ============ mega QKV: 1536 blocks of 128x128; Q (512) + KV (1024) ==========
// (R0/R6-verified: ~64-66 us, MfmaUtil 33-34%, FETCH ~52 MB, XCD co-location)
__global__ __launch_bounds__(256, 4) void qkv_kernel(
    const unsigned short* __restrict__ xb, const unsigned short* __restrict__ cb,
    const unsigned short* __restrict__ WtQ, const unsigned short* __restrict__ WtKV,
    const float* __restrict__ bq, const float* __restrict__ bk, const float* __restrict__ bv,
    unsigned short* __restrict__ Qb, unsigned short* __restrict__ Kb,
    unsigned short* __restrict__ Vt) {
    __shared__ unsigned short As[128 * 64];
    __shared__ unsigned short Bs[128 * 64];
    const int i = blockIdx.x;
    const bool isQ = i < 512;
    int by, bxcol;
    const unsigned short *A, *B;
    if (isQ) {
        const int slot = i >> 3;
        by = (i & 7) + 8 * (slot & 7);
        const int bx = slot >> 3; bxcol = bx * 128;
        A = xb + (size_t)by * 128 * 1024;
        B = WtQ + (size_t)bx * 128 * 1024;
    } else {
        const int j = i - 512;
        const int slot = j >> 3;
        by = (j & 7) + 8 * (slot & 7);
        const int bx = slot >> 3; bxcol = bx * 128;
        A = cb + (size_t)by * 128 * 1024;
        B = WtKV + (size_t)bx * 128 * 1024;
    }
    floatx16 acc[2][2];
#pragma unroll
    for (int a = 0; a < 2; ++a)
#pragma unroll
        for (int bj = 0; bj < 2; ++bj)
#pragma unroll
            for (int r = 0; r < 16; ++r) acc[a][bj][r] = 0.f;

    gemm_core(A, 1024, B, 1024, 1024, As, Bs, acc);

    const int wave = threadIdx.x >> 6, lane = threadIdx.x & 63;
    const int kg = lane >> 5;
    const int cm = by * 128 + (wave >> 1) * 64;
    const int cn = bxcol + (wave & 1) * 64 + (lane & 31);
    if (isQ || bxcol < 1024) {
        unsigned short* O = isQ ? Qb : Kb;
        const float* bias = isQ ? bq : bk;
#pragma unroll
        for (int nt = 0; nt < 2; ++nt) {
            const int col = cn + nt * 32;
            const float bvv = bias[col];
#pragma unroll
            for (int mt = 0; mt < 2; ++mt)
#pragma unroll
                for (int r = 0; r < 16; ++r) {
                    const int row = cm + mt * 32 + EPI_ROW(r, kg);
                    O[(size_t)row * 1024 + col] = f2bf(acc[mt][nt][r] + bvv);
                }
        }
    } else {
        // V half -> transposed write: Vt[b][colv][q]; 4 consecutive q per reg-quad
#pragma unroll
        for (int nt = 0; nt < 2; ++nt) {
            const int colv = cn + nt * 32 - 1024;
            const float bvv = bv[colv];
#pragma unroll
            for (int mt = 0; mt < 2; ++mt) {
                const int rowg = cm + mt * 32 + 4 * kg;
                const int b = rowg >> 11, qb = rowg & 2047;
#pragma unroll
                for (int g = 0; g < 4; ++g) {
                    const int q = qb + 8 * g;
                    ushort4 u;
                    u.x = f2bf(acc[mt][nt][g * 4 + 0] + bvv);
                    u.y = f2bf(acc[mt][nt][g * 4 + 1] + bvv);
                    u.z = f2bf(acc[mt][nt][g * 4 + 2] + bvv);
                    u.w = f2bf(acc[mt][nt][g * 4 + 3] + bvv);
                    *reinterpret_cast<ushort4*>(Vt + (size_t)b * 2097152 + (size_t)colv * 2048 + q) = u;
                }
            }
        }
    }
}

// ============ P_unnorm = exp(Q K^T * scale); row sums -> l via atomics ========
// (R0/R6-verified body; logits bounded so no max-subtract needed)
__global__ __launch_bounds__(256, 4) void qkt_kernel(
    const unsigned short* __restrict__ Qb, const unsigned short* __restrict__ Kb,
    unsigned short* __restrict__ Sb, float* __restrict__ l) {
    __shared__ unsigned short As[128 * 64];
    __shared__ unsigned short Bs[128 * 64];
    const int i = blockIdx.x;                    // 0..1023
    const int z = (i >> 1) & 3;
    const int slot = i >> 3;
    const int by = (i & 1) + 2 * (slot & 7);
    const int bx = slot >> 3;
    const unsigned short* A = Qb + (size_t)z * 2097152 + (size_t)by * 128 * 1024;
    const unsigned short* B = Kb + (size_t)z * 2097152 + (size_t)bx * 128 * 1024;
    floatx16 acc[2][2];
#pragma unroll
    for (int a = 0; a < 2; ++a)
#pragma unroll
        for (int bj = 0; bj < 2; ++bj)
#pragma unroll
            for (int r = 0; r < 16; ++r) acc[a][bj][r] = 0.f;

    gemm_core(A, 1024, B, 1024, 1024, As, Bs, acc);

    const int wave = threadIdx.x >> 6, lane = threadIdx.x & 63;
    const int kg = lane >> 5;
    unsigned short* C = Sb + (size_t)z * 4194304;
    float* lz = l + z * 2048;
    const int cm = by * 128 + (wave >> 1) * 64;
    const int cn = bx * 128 + (wave & 1) * 64 + (lane & 31);
#pragma unroll
    for (int mt = 0; mt < 2; ++mt)
#pragma unroll
        for (int r = 0; r < 16; ++r) {
            const int row = cm + mt * 32 + EPI_ROW(r, kg);
            const float e0 = __expf(acc[mt][0][r] * 0.03125f);
            const float e1 = __expf(acc[mt][1][r] * 0.03125f);
            C[(size_t)row * 2048 + cn] = f2bf(e0);
            C[(size_t)row * 2048 + cn + 32] = f2bf(e1);
            float s = e0 + e1;
            s += __shfl_xor(s, 1);  s += __shfl_xor(s, 2);
            s += __shfl_xor(s, 4);  s += __shfl_xor(s, 8);
            s += __shfl_xor(s, 16);
            if ((lane & 31) == (mt * 16 + r)) atomicAdd(&lz[row], s);
        }
}

// ============ out = (P_unnorm @ Vt^T) / l[row] (fp32 out) ============
// (R0/R6-verified body)
__global__ __launch_bounds__(256, 4) void pv_kernel(
    const unsigned short* __restrict__ Sb, const unsigned short* __restrict__ Vt,
    const float* __restrict__ l, float* __restrict__ out) {
    __shared__ unsigned short As[128 * 64];
    __shared__ unsigned short Bs[128 * 64];
    const int i = blockIdx.x;                    // 0..511
    const int z = (i >> 1) & 3;
    const int slot = i >> 3;
    const int by = (i & 1) + 2 * (slot & 7);
    const int bx = slot >> 3;
    const unsigned short* A = Sb + (size_t)z * 4194304 + (size_t)by * 128 * 2048;
    const unsigned short* B = Vt + (size_t)z * 2097152 + (size_t)bx * 128 * 2048;
    floatx16 acc[2][2];
#pragma unroll
    for (int a = 0; a < 2; ++a)
#pragma unroll
        for (int bj = 0; bj < 2; ++bj)
#pragma unroll
            for (int r = 0; r < 16; ++r) acc[a][bj][r] = 0.f;

    gemm_core(A, 2048, B, 2048, 2048, As, Bs, acc);

    const int wave = threadIdx.x >> 6, lane = threadIdx.x & 63;
    const int kg = lane >> 5;
    float* C = out + (size_t)z * 2097152;
    const float* lz = l + z * 2048;
    const int cm = by * 128 + (wave >> 1) * 64;
    const int cn = bx * 128 + (wave & 1) * 64 + (lane & 31);
#pragma unroll
    for (int mt = 0; mt < 2; ++mt)
#pragma unroll
        for (int r = 0; r < 16; ++r) {
            const int row = cm + mt * 32 + EPI_ROW(r, kg);
            const float inv = 1.0f / lz[row];
            C[(size_t)row * 1024 + cn] = acc[mt][0][r] * inv;
            C[(size_t)row * 1024 + cn + 32] = acc[mt][1][r] * inv;
        }
}

extern "C" void kernel_launch(void* const* d_in, const int* in_sizes, int n_in,
                              void* d_out, int out_size, void* d_ws, size_t ws_size,
                              hipStream_t stream) {
    const float* x   = (const float*)d_in[0];
    const float* ctx = (const float*)d_in[1];
    const float* Wq  = (const float*)d_in[2];
    const float* bq  = (const float*)d_in[3];
    const float* Wk  = (const float*)d_in[4];
    const float* bk  = (const float*)d_in[5];
    const float* Wv  = (const float*)d_in[6];
    const float* bv  = (const float*)d_in[7];
    float* out = (float*)d_out;

    const size_t MB = 1024 * 1024;
    char* ws = (char*)d_ws;
    unsigned short* xb   = (unsigned short*)(ws + 0 * MB);
    unsigned short* cb   = (unsigned short*)(ws + 16 * MB);
    unsigned short* Qb   = (unsigned short*)(ws + 32 * MB);
    unsigned short* Kb   = (unsigned short*)(ws + 48 * MB);
    unsigned short* Vt   = (unsigned short*)(ws + 64 * MB);
    unsigned short* Wt0  = (unsigned short*)(ws + 80 * MB);
    unsigned short* WtKV = (unsigned short*)(ws + 82 * MB);
    unsigned short* Sb   = (unsigned short*)(ws + 86 * MB);
    float*          lrow = (float*)(ws + 118 * MB);   // 8192 fp32 row sums

    prep_kernel<<<16384 + 3072 + 8, 256, 0, stream>>>(
        x, ctx, Wq, Wk, Wv, xb, cb, Wt0, WtKV, lrow);
    qkv_kernel<<<1536, 256, 0, stream>>>(xb, cb, Wt0, WtKV, bq, bk, bv, Qb, Kb, Vt);
    qkt_kernel<<<1024, 256, 0, stream>>>(Qb, Kb, Sb, lrow);
    pv_kernel<<<512, 256, 0, stream>>>(Sb, Vt, lrow, out);
}